// Round 1
// baseline (1317.481 us; speedup 1.0000x reference)
//
#include <hip/hip_runtime.h>
#include <stdint.h>

#define Bq 8
#define Hh 8
#define Ss 1024
#define Dd 64
#define Cc 21

typedef short bf16x8 __attribute__((ext_vector_type(8)));
typedef float f32x4 __attribute__((ext_vector_type(4)));

__device__ __forceinline__ unsigned short f2bf(float f) {
  union { float f; uint32_t u; } v; v.f = f;
  uint32_t u = v.u;
  u += 0x7FFFu + ((u >> 16) & 1u);  // round-to-nearest-even
  return (unsigned short)(u >> 16);
}

// K0: bias[b,h,q,k] = sum_c dtw[b,c,q,k]*W[h,c] + b[h], masked -> -1e9.
// Written into the attention region of d_out (scratch; overwritten by K1).
// Block = one (b,q) row, 256 threads x 4 k each.
__global__ __launch_bounds__(256) void bias_kernel(
    const float* __restrict__ dtw, const int* __restrict__ mask,
    const float* __restrict__ W, const float* __restrict__ bv,
    float* __restrict__ attn) {
  __shared__ float sW[Hh * Cc];
  __shared__ float sb[Hh];
  int t = threadIdx.x;
  if (t < Hh * Cc) sW[t] = W[t];
  if (t < Hh) sb[t] = bv[t];
  __syncthreads();
  int b = blockIdx.x >> 10;
  int q = blockIdx.x & 1023;
  int k = t << 2;
  size_t dbase = (((size_t)b * Cc) * Ss + q) * Ss + k;
  float acc[Hh][4];
#pragma unroll
  for (int h = 0; h < Hh; ++h) {
    float bb = sb[h];
    acc[h][0] = bb; acc[h][1] = bb; acc[h][2] = bb; acc[h][3] = bb;
  }
  for (int c = 0; c < Cc; ++c) {
    float4 dv = *(const float4*)(dtw + dbase + (size_t)c * Ss * Ss);
#pragma unroll
    for (int h = 0; h < Hh; ++h) {
      float w = sW[h * Cc + c];
      acc[h][0] += w * dv.x; acc[h][1] += w * dv.y;
      acc[h][2] += w * dv.z; acc[h][3] += w * dv.w;
    }
  }
  int4 mv = *(const int4*)(mask + ((size_t)b * Ss + q) * Ss + k);
#pragma unroll
  for (int h = 0; h < Hh; ++h) {
    float4 o;
    o.x = (mv.x == 0) ? -1e9f : acc[h][0];
    o.y = (mv.y == 0) ? -1e9f : acc[h][1];
    o.z = (mv.z == 0) ? -1e9f : acc[h][2];
    o.w = (mv.w == 0) ? -1e9f : acc[h][3];
    *(float4*)(attn + ((((size_t)b * Hh + h) * Ss + q) * Ss + k)) = o;
  }
}

// K1: per (b,h,q-tile of 32). Phase1: scores = QK^T/8 + bias (in place in
// attn buffer), accumulate sum(exp(s)) per row. Phase2: p = exp(s)/l,
// write attention, out = P@V via MFMA.
// Wave w: mtile = w&1 (16 q-rows), phase1 cols = (w>>1)*32 of each 64-tile;
// phase2 k-parity = w>>1. Each wave re-reads exactly the cells it wrote.
__global__ __launch_bounds__(256) void attn_kernel(
    const float* __restrict__ Q, const float* __restrict__ K,
    const float* __restrict__ V, float* __restrict__ out,
    float* __restrict__ attn) {
  __shared__ unsigned short qtile[32][72];  // bf16 Q/8, +8 pad (bank spread)
  __shared__ unsigned short kvt[64][72];    // phase1: K rows; phase2: V^T
  __shared__ float red[4][16];
  __shared__ float linv[32];
  __shared__ float omerge[32][64];

  int t = threadIdx.x;
  int w = t >> 6;
  int lane = t & 63;
  int quad = lane >> 4;
  int l16 = lane & 15;

  int qt = blockIdx.x & 31;
  int bh = blockIdx.x >> 5;
  int q0 = qt << 5;

  const float* Qp = Q + ((size_t)bh * Ss + q0) * Dd;
  const float* Kp = K + (size_t)bh * Ss * Dd;
  const float* Vp = V + (size_t)bh * Ss * Dd;
  float* attp = attn + (size_t)bh * Ss * Ss + (size_t)q0 * Ss;
  float* outp = out + ((size_t)bh * Ss + q0) * Dd;

  // stage Q tile (scaled by 1/8) as bf16
  {
    int row = t >> 3;
    int col = (t & 7) << 3;
    float4 a = *(const float4*)(Qp + row * Dd + col);
    float4 b2 = *(const float4*)(Qp + row * Dd + col + 4);
    qtile[row][col + 0] = f2bf(a.x * 0.125f);
    qtile[row][col + 1] = f2bf(a.y * 0.125f);
    qtile[row][col + 2] = f2bf(a.z * 0.125f);
    qtile[row][col + 3] = f2bf(a.w * 0.125f);
    qtile[row][col + 4] = f2bf(b2.x * 0.125f);
    qtile[row][col + 5] = f2bf(b2.y * 0.125f);
    qtile[row][col + 6] = f2bf(b2.z * 0.125f);
    qtile[row][col + 7] = f2bf(b2.w * 0.125f);
  }

  int mt = w & 1;
  int ntb = (w >> 1) << 1;
  int mrow = mt * 16 + l16;  // A-frag row for this lane
  float lsum[4] = {0.f, 0.f, 0.f, 0.f};

  // ---------------- Phase 1: scores + row sum(exp) ----------------
  for (int kt = 0; kt < 16; ++kt) {
    int k0 = kt << 6;
    __syncthreads();  // prior-iter kvt reads done (also covers Q staging)
    {
      int row = t >> 2;
      int colb = (t & 3) << 4;
#pragma unroll
      for (int i = 0; i < 4; ++i) {
        float4 v4 = *(const float4*)(Kp + (size_t)(k0 + row) * Dd + colb + i * 4);
        kvt[row][colb + i * 4 + 0] = f2bf(v4.x);
        kvt[row][colb + i * 4 + 1] = f2bf(v4.y);
        kvt[row][colb + i * 4 + 2] = f2bf(v4.z);
        kvt[row][colb + i * 4 + 3] = f2bf(v4.w);
      }
    }
    __syncthreads();
#pragma unroll
    for (int nti = 0; nti < 2; ++nti) {
      int nt = ntb + nti;
      f32x4 acc = {0.f, 0.f, 0.f, 0.f};
#pragma unroll
      for (int ks = 0; ks < 2; ++ks) {
        bf16x8 af = *(const bf16x8*)&qtile[mrow][ks * 32 + quad * 8];
        bf16x8 bfr = *(const bf16x8*)&kvt[nt * 16 + l16][ks * 32 + quad * 8];
        acc = __builtin_amdgcn_mfma_f32_16x16x32_bf16(af, bfr, acc, 0, 0, 0);
      }
      int kcol = k0 + nt * 16 + l16;
      int rb = mt * 16 + quad * 4;
#pragma unroll
      for (int r = 0; r < 4; ++r) {
        float* sp = attp + (size_t)(rb + r) * Ss + kcol;
        float sc = acc[r] + *sp;  // bias (masked cells: -1e9 + qk == -1e9)
        *sp = sc;
        lsum[r] += __expf(sc);
      }
    }
  }
  // reduce over the 16 lanes holding the same 4 rows
#pragma unroll
  for (int off = 1; off < 16; off <<= 1) {
#pragma unroll
    for (int r = 0; r < 4; ++r) lsum[r] += __shfl_xor(lsum[r], off, 64);
  }
  if (l16 == 0) {
#pragma unroll
    for (int r = 0; r < 4; ++r) red[w][quad * 4 + r] = lsum[r];
  }
  __syncthreads();
  if (t < 32) {
    int mtt = t >> 4, rl = t & 15;
    linv[t] = 1.0f / (red[mtt][rl] + red[mtt + 2][rl]);
  }
  __syncthreads();

  // ---------------- Phase 2: attention + P@V ----------------
  int par = w >> 1;
  float li = linv[mrow];
  f32x4 oacc[4];
#pragma unroll
  for (int dt = 0; dt < 4; ++dt) {
    oacc[dt][0] = 0.f; oacc[dt][1] = 0.f; oacc[dt][2] = 0.f; oacc[dt][3] = 0.f;
  }
  for (int it = 0; it < 16; ++it) {
    int k0 = it << 6;
    __syncthreads();  // prior-iter kvt reads done
    {
      int row = t >> 2;          // k index within tile
      int colb = (t & 3) << 4;   // d index
#pragma unroll
      for (int i = 0; i < 4; ++i) {
        float4 v4 = *(const float4*)(Vp + (size_t)(k0 + row) * Dd + colb + i * 4);
        kvt[colb + i * 4 + 0][row] = f2bf(v4.x);  // V^T: [d][k]
        kvt[colb + i * 4 + 1][row] = f2bf(v4.y);
        kvt[colb + i * 4 + 2][row] = f2bf(v4.z);
        kvt[colb + i * 4 + 3][row] = f2bf(v4.w);
      }
    }
    __syncthreads();
    int ks = k0 + par * 32;
    float* sp = attp + (size_t)mrow * Ss + ks + quad * 8;
    float4 s0 = *(const float4*)sp;
    float4 s1 = *(const float4*)(sp + 4);
    float p0 = __expf(s0.x) * li, p1 = __expf(s0.y) * li;
    float p2 = __expf(s0.z) * li, p3 = __expf(s0.w) * li;
    float p4 = __expf(s1.x) * li, p5 = __expf(s1.y) * li;
    float p6 = __expf(s1.z) * li, p7 = __expf(s1.w) * li;
    *(float4*)sp = make_float4(p0, p1, p2, p3);
    *(float4*)(sp + 4) = make_float4(p4, p5, p6, p7);
    bf16x8 af;
    af[0] = (short)f2bf(p0); af[1] = (short)f2bf(p1);
    af[2] = (short)f2bf(p2); af[3] = (short)f2bf(p3);
    af[4] = (short)f2bf(p4); af[5] = (short)f2bf(p5);
    af[6] = (short)f2bf(p6); af[7] = (short)f2bf(p7);
#pragma unroll
    for (int dt = 0; dt < 4; ++dt) {
      bf16x8 bfr = *(const bf16x8*)&kvt[dt * 16 + l16][par * 32 + quad * 8];
      oacc[dt] = __builtin_amdgcn_mfma_f32_16x16x32_bf16(af, bfr, oacc[dt], 0, 0, 0);
    }
  }
  // merge k-parities and store output
  __syncthreads();
  if (par == 0) {
#pragma unroll
    for (int dt = 0; dt < 4; ++dt)
#pragma unroll
      for (int r = 0; r < 4; ++r)
        omerge[mt * 16 + quad * 4 + r][dt * 16 + l16] = oacc[dt][r];
  }
  __syncthreads();
  if (par == 1) {
#pragma unroll
    for (int dt = 0; dt < 4; ++dt)
#pragma unroll
      for (int r = 0; r < 4; ++r)
        omerge[mt * 16 + quad * 4 + r][dt * 16 + l16] += oacc[dt][r];
  }
  __syncthreads();
  {
    int row = t >> 3;
    int col = (t & 7) << 3;
    float4 o0 = *(const float4*)&omerge[row][col];
    float4 o1 = *(const float4*)&omerge[row][col + 4];
    *(float4*)(outp + row * Dd + col) = o0;
    *(float4*)(outp + row * Dd + col + 4) = o1;
  }
}

extern "C" void kernel_launch(void* const* d_in, const int* in_sizes, int n_in,
                              void* d_out, int out_size, void* d_ws, size_t ws_size,
                              hipStream_t stream) {
  const float* Q = (const float*)d_in[0];
  const float* K = (const float*)d_in[1];
  const float* V = (const float*)d_in[2];
  const float* dtw = (const float*)d_in[3];
  const int* mask = (const int*)d_in[4];
  const float* W = (const float*)d_in[5];
  const float* bv = (const float*)d_in[6];
  float* out = (float*)d_out;
  float* attn = out + (size_t)Bq * Hh * Ss * Dd;  // attention region of d_out

  bias_kernel<<<Bq * Ss, 256, 0, stream>>>(dtw, mask, W, bv, attn);
  attn_kernel<<<Bq * Hh * (Ss / 32), 256, 0, stream>>>(Q, K, V, out, attn);
}